// Round 7
// baseline (162.110 us; speedup 1.0000x reference)
//
#include <hip/hip_runtime.h>
#include <math.h>

typedef __attribute__((ext_vector_type(2))) float f32x2;

#define BB 4
#define HH 2048
#define WW 128
#define HP (HH + 2)   // 2050
#define WP (WW + 2)   // 130
#define PP 128        // pooled size
#define ROWS 4

#define BORDER_PER_B (2 * WP + 2 * (HP - 2))   // 4356

// ---------------------------------------------------------------------------
// Kernel 1: border-zero of xp (fused) + adaptive avg pool + 1x1 conv + sigmoid
// grid 512x128 = 65536 threads >= 4*4356 border cells.
// ---------------------------------------------------------------------------
__global__ void k_fm(const float* __restrict__ rgb, const float* __restrict__ w_fm,
                     float* __restrict__ fm, float4* __restrict__ xp) {
    int j = threadIdx.x;              // 0..127
    int bi = blockIdx.x;              // b*128 + i
    int tid = bi * 128 + j;

    // ---- fused pad-border zeroing (interior overwritten by k_mat) ----
    if (tid < BB * BORDER_PER_B) {
        int b = tid / BORDER_PER_B;
        int r = tid - b * BORDER_PER_B;
        int row, col;
        if (r < WP)          { row = 0;      col = r; }
        else if (r < 2 * WP) { row = HP - 1; col = r - WP; }
        else {
            int q = r - 2 * WP;
            row = 1 + (q >> 1);
            col = (q & 1) ? (WP - 1) : 0;
        }
        xp[((size_t)b * HP + row) * WP + col] = make_float4(0.f, 0.f, 0.f, 0.f);
    }

    int b = bi >> 7, i = bi & 127;
    const float* r0 = rgb + ((size_t)(b * 2 + 0) * HH + (size_t)i * 16) * WW + j;
    const float* r1 = rgb + ((size_t)(b * 2 + 1) * HH + (size_t)i * 16) * WW + j;
    float s0 = 0.f, s1 = 0.f;
#pragma unroll
    for (int a = 0; a < 16; ++a) { s0 += r0[a * WW]; s1 += r1[a * WW]; }
    s0 *= (1.f / 16.f); s1 *= (1.f / 16.f);
    float f0 = w_fm[0] * s0 + w_fm[1] * s1;
    float f1 = w_fm[2] * s0 + w_fm[3] * s1;
    fm[((size_t)(b * 2 + 0) * PP + i) * PP + j] = 1.f / (1.f + expf(-f0));
    fm[((size_t)(b * 2 + 1) * PP + i) * PP + j] = 1.f / (1.f + expf(-f1));
}

// ---------------------------------------------------------------------------
// Kernel 2: mat = rgb @ fm + rgb (per b,c), fs = w_fs @ mat,
//           pack xp cell = float4 (sar0,sar1,fs0,fs1).
// ---------------------------------------------------------------------------
__global__ __launch_bounds__(128) void k_mat(
        const float* __restrict__ rgb, const float* __restrict__ sar,
        const float* __restrict__ w_fs, const float* __restrict__ fm,
        float* __restrict__ xp) {
    int w = threadIdx.x;              // 0..127
    int blk = blockIdx.x;
    int b = blk / (HH / ROWS);
    int h0 = (blk % (HH / ROWS)) * ROWS;

    const float* rg0 = rgb + ((size_t)(b * 2 + 0) * HH + h0) * WW;  // uniform base
    const float* rg1 = rgb + ((size_t)(b * 2 + 1) * HH + h0) * WW;
    const float* fm0 = fm + (size_t)(b * 2 + 0) * PP * PP;
    const float* fm1 = fm + (size_t)(b * 2 + 1) * PP * PP;

    float acc0[ROWS], acc1[ROWS];
#pragma unroll
    for (int r = 0; r < ROWS; ++r) {                 // residual term
        acc0[r] = rg0[r * WW + w];
        acc1[r] = rg1[r * WW + w];
    }

#pragma unroll 4
    for (int k4 = 0; k4 < PP; k4 += 4) {
        float f0[4], f1[4];
#pragma unroll
        for (int t = 0; t < 4; ++t) {
            f0[t] = fm0[(size_t)(k4 + t) * PP + w];  // coalesced vector load
            f1[t] = fm1[(size_t)(k4 + t) * PP + w];
        }
#pragma unroll
        for (int r = 0; r < ROWS; ++r) {
            float4 a0 = *(const float4*)(rg0 + r * WW + k4);   // uniform -> s_load
            float4 a1 = *(const float4*)(rg1 + r * WW + k4);
            acc0[r] += a0.x * f0[0] + a0.y * f0[1] + a0.z * f0[2] + a0.w * f0[3];
            acc1[r] += a1.x * f1[0] + a1.y * f1[1] + a1.z * f1[2] + a1.w * f1[3];
        }
    }

    float wa = w_fs[0], wb = w_fs[1], wc = w_fs[2], wd = w_fs[3];
#pragma unroll
    for (int r = 0; r < ROWS; ++r) {
        float m0 = acc0[r], m1 = acc1[r];
        float fs0 = wa * m0 + wb * m1;
        float fs1 = wc * m0 + wd * m1;
        float s0 = sar[((size_t)(b * 2 + 0) * HH + (h0 + r)) * WW + w];
        float s1 = sar[((size_t)(b * 2 + 1) * HH + (h0 + r)) * WW + w];
        float4 v = make_float4(s0, s1, fs0, fs1);
        *(float4*)(xp + (((size_t)b * HP + (h0 + r + 1)) * WP + (w + 1)) * 4) = v;
    }
}

// ---------------------------------------------------------------------------
// Kernel 3: offset conv + deformable bilinear + deform conv, 2 px/thread.
// Pixel-pair arithmetic packed as f32x2 -> v_pk_{fma,mul,add}_f32 (2 exact
// f32 ops/inst). floor/clamp/cvt/gather/combine stay scalar (exact semantics,
// no profitable packing). Weights via uniform s_load.
// ---------------------------------------------------------------------------
__global__ __launch_bounds__(256, 2) void k_deform(
        const float* __restrict__ w_p, const float* __restrict__ b_p,
        const float* __restrict__ w_dc, const float* __restrict__ xp,
        float* __restrict__ out) {
    int idx = blockIdx.x * 256 + threadIdx.x;   // 0 .. B*(H/2)*W-1
    int b = idx >> 17;                          // (H/2)*W = 131072 = 2^17
    int rem = idx & ((HH / 2) * WW - 1);
    int h2 = rem >> 7;                          // W = 128 = 2^7
    int w = rem & (WW - 1);
    int h = h2 * 2;                             // pixels (h,w) and (h+1,w)

    const float4* xpb = (const float4*)xp + (size_t)b * HP * WP;

    // 4 rows x 3 cols neighborhood (float4 = 4 channels per point)
    float4 nb4[4][3];
#pragma unroll
    for (int dy = 0; dy < 4; ++dy)
#pragma unroll
        for (int dx = 0; dx < 3; ++dx)
            nb4[dy][dx] = xpb[(h + dy) * WP + (w + dx)];

    // ---- offset conv, packed over the pixel pair ----
    f32x2 off2[18];
#pragma unroll
    for (int r = 0; r < 18; ++r) {
        float bias = b_p[r];                    // uniform -> s_load
        off2[r] = (f32x2){bias, bias};
    }
#pragma unroll
    for (int ky = 0; ky < 3; ++ky) {
#pragma unroll
        for (int kx = 0; kx < 3; ++kx) {
            f32x2 p0 = {nb4[ky][kx].x, nb4[ky + 1][kx].x};
            f32x2 p1 = {nb4[ky][kx].y, nb4[ky + 1][kx].y};
            f32x2 p2 = {nb4[ky][kx].z, nb4[ky + 1][kx].z};
            f32x2 p3 = {nb4[ky][kx].w, nb4[ky + 1][kx].w};
#pragma unroll
            for (int r = 0; r < 18; ++r) {
                const float* wr = w_p + r * 36 + ky * 3 + kx;  // uniform s_load
                off2[r] += wr[0] * p0 + wr[9] * p1 + wr[18] * p2 + wr[27] * p3;
            }
        }
    }

    float acc0[2] = {0.f, 0.f};
    float acc1[2] = {0.f, 0.f};
#pragma unroll
    for (int n = 0; n < 9; ++n) {
        int pny = n / 3 - 1;
        int pnx = n % 3 - 1;
        // packed coordinates for the pixel pair
        f32x2 py2 = (f32x2){(float)(h + 1 + pny), (float)(h + 2 + pny)} + off2[n];
        f32x2 px2 = (float)(w + 1 + pnx) + off2[9 + n];
        f32x2 fy2 = {floorf(py2.x), floorf(py2.y)};
        f32x2 fx2 = {floorf(px2.x), floorf(px2.y)};
        // clamps (scalar per component — v_med3)
        f32x2 y0f = {fminf(fmaxf(fy2.x, 0.f), (float)(HP - 1)),
                     fminf(fmaxf(fy2.y, 0.f), (float)(HP - 1))};
        f32x2 y1f = {fminf(fmaxf(fy2.x + 1.f, 0.f), (float)(HP - 1)),
                     fminf(fmaxf(fy2.y + 1.f, 0.f), (float)(HP - 1))};
        f32x2 x0f = {fminf(fmaxf(fx2.x, 0.f), (float)(WP - 1)),
                     fminf(fmaxf(fx2.y, 0.f), (float)(WP - 1))};
        f32x2 x1f = {fminf(fmaxf(fx2.x + 1.f, 0.f), (float)(WP - 1)),
                     fminf(fmaxf(fx2.y + 1.f, 0.f), (float)(WP - 1))};
        f32x2 pyc = {fminf(fmaxf(py2.x, 0.f), (float)(HP - 1)),
                     fminf(fmaxf(py2.y, 0.f), (float)(HP - 1))};
        f32x2 pxc = {fminf(fmaxf(px2.x, 0.f), (float)(WP - 1)),
                     fminf(fmaxf(px2.y, 0.f), (float)(WP - 1))};
        // packed interp-weight arithmetic
        f32x2 ay = 1.f + (y0f - pyc);
        f32x2 by = 1.f - (y1f - pyc);
        f32x2 ax = 1.f + (x0f - pxc);
        f32x2 bx = 1.f - (x1f - pxc);
        f32x2 glt = ay * ax, grb = by * bx, glb = ay * bx, grt = by * ax;

#pragma unroll
        for (int p = 0; p < 2; ++p) {
            int y0 = (int)(p ? y0f.y : y0f.x);
            int y1 = (int)(p ? y1f.y : y1f.x);
            int x0 = (int)(p ? x0f.y : x0f.x);
            int x1 = (int)(p ? x1f.y : x1f.x);
            float g_lt = p ? glt.y : glt.x;
            float g_rb = p ? grb.y : grb.x;
            float g_lb = p ? glb.y : glb.x;
            float g_rt = p ? grt.y : grt.x;

            int r0 = y0 * WP, r1 = y1 * WP;     // int32 addressing
            float4 v_lt = xpb[r0 + x0];
            float4 v_rb = xpb[r1 + x1];
            float4 v_lb = xpb[r0 + x1];
            float4 v_rt = xpb[r1 + x0];

            float vx = g_lt * v_lt.x + g_rb * v_rb.x + g_lb * v_lb.x + g_rt * v_rt.x;
            float vy = g_lt * v_lt.y + g_rb * v_rb.y + g_lb * v_lb.y + g_rt * v_rt.y;
            float vz = g_lt * v_lt.z + g_rb * v_rb.z + g_lb * v_lb.z + g_rt * v_rt.z;
            float vw = g_lt * v_lt.w + g_rb * v_rb.w + g_lb * v_lb.w + g_rt * v_rt.w;

            acc0[p] += vx * w_dc[0 * 36 + 0 * 9 + n] + vy * w_dc[0 * 36 + 1 * 9 + n]
                     + vz * w_dc[0 * 36 + 2 * 9 + n] + vw * w_dc[0 * 36 + 3 * 9 + n];
            acc1[p] += vx * w_dc[1 * 36 + 0 * 9 + n] + vy * w_dc[1 * 36 + 1 * 9 + n]
                     + vz * w_dc[1 * 36 + 2 * 9 + n] + vw * w_dc[1 * 36 + 3 * 9 + n];
        }
    }
#pragma unroll
    for (int p = 0; p < 2; ++p) {
        out[((size_t)(b * 2 + 0) * HH + (h + p)) * WW + w] = acc0[p];
        out[((size_t)(b * 2 + 1) * HH + (h + p)) * WW + w] = acc1[p];
    }
}

// ---------------------------------------------------------------------------
extern "C" void kernel_launch(void* const* d_in, const int* in_sizes, int n_in,
                              void* d_out, int out_size, void* d_ws, size_t ws_size,
                              hipStream_t stream) {
    const float* rgb  = (const float*)d_in[0];
    const float* sar  = (const float*)d_in[1];
    const float* w_fm = (const float*)d_in[2];
    const float* w_fs = (const float*)d_in[3];
    const float* w_p  = (const float*)d_in[4];
    const float* b_p  = (const float*)d_in[5];
    const float* w_dc = (const float*)d_in[6];
    float* out = (float*)d_out;

    // ws layout: fm [131072 f32] | xp [B*HP*WP float4]
    float* ws = (float*)d_ws;
    float* fm = ws;
    float* xp = ws + 131072;                           // 16B aligned

    k_fm<<<BB * 128, 128, 0, stream>>>(rgb, w_fm, fm, (float4*)xp);
    k_mat<<<BB * (HH / ROWS), 128, 0, stream>>>(rgb, sar, w_fs, fm, xp);
    k_deform<<<(BB * (HH / 2) * WW) / 256, 256, 0, stream>>>(w_p, b_p, w_dc, xp, out);
}

// Round 8
// 80.639 us; speedup vs baseline: 2.0103x; 2.0103x over previous
//
#include <hip/hip_runtime.h>
#include <math.h>

typedef __attribute__((ext_vector_type(2))) float f32x2;

#define BB 4
#define HH 2048
#define WW 128
#define HP (HH + 2)   // 2050
#define WP (WW + 2)   // 130
#define PP 128        // pooled size
#define ROWS 8

#define BORDER_PER_B (2 * WP + 2 * (HP - 2))   // 4356

// ---------------------------------------------------------------------------
// Kernel 1: border-zero of xp (fused) + adaptive avg pool + 1x1 conv + sigmoid
// ---------------------------------------------------------------------------
__global__ void k_fm(const float* __restrict__ rgb, const float* __restrict__ w_fm,
                     float* __restrict__ fm, float4* __restrict__ xp) {
    int j = threadIdx.x;              // 0..127
    int bi = blockIdx.x;              // b*128 + i
    int tid = bi * 128 + j;

    // ---- fused pad-border zeroing (interior overwritten by k_mat) ----
    if (tid < BB * BORDER_PER_B) {
        int b = tid / BORDER_PER_B;
        int r = tid - b * BORDER_PER_B;
        int row, col;
        if (r < WP)          { row = 0;      col = r; }
        else if (r < 2 * WP) { row = HP - 1; col = r - WP; }
        else {
            int q = r - 2 * WP;
            row = 1 + (q >> 1);
            col = (q & 1) ? (WP - 1) : 0;
        }
        xp[((size_t)b * HP + row) * WP + col] = make_float4(0.f, 0.f, 0.f, 0.f);
    }

    int b = bi >> 7, i = bi & 127;
    const float* r0 = rgb + ((size_t)(b * 2 + 0) * HH + (size_t)i * 16) * WW + j;
    const float* r1 = rgb + ((size_t)(b * 2 + 1) * HH + (size_t)i * 16) * WW + j;
    float s0 = 0.f, s1 = 0.f;
#pragma unroll
    for (int a = 0; a < 16; ++a) { s0 += r0[a * WW]; s1 += r1[a * WW]; }
    s0 *= (1.f / 16.f); s1 *= (1.f / 16.f);
    float f0 = w_fm[0] * s0 + w_fm[1] * s1;
    float f1 = w_fm[2] * s0 + w_fm[3] * s1;
    fm[((size_t)(b * 2 + 0) * PP + i) * PP + j] = 1.f / (1.f + expf(-f0));
    fm[((size_t)(b * 2 + 1) * PP + i) * PP + j] = 1.f / (1.f + expf(-f1));
}

// ---------------------------------------------------------------------------
// Kernel 2: mat = rgb @ fm + rgb (per b,c), fs = w_fs @ mat,
//           pack xp cell = float4 (sar0,sar1,fs0,fs1).
// ROWS=8: halves the per-block fm re-read (L2 traffic 268->134 MB).
// ---------------------------------------------------------------------------
__global__ __launch_bounds__(128) void k_mat(
        const float* __restrict__ rgb, const float* __restrict__ sar,
        const float* __restrict__ w_fs, const float* __restrict__ fm,
        float* __restrict__ xp) {
    int w = threadIdx.x;              // 0..127
    int blk = blockIdx.x;
    int b = blk / (HH / ROWS);
    int h0 = (blk % (HH / ROWS)) * ROWS;

    const float* rg0 = rgb + ((size_t)(b * 2 + 0) * HH + h0) * WW;  // uniform base
    const float* rg1 = rgb + ((size_t)(b * 2 + 1) * HH + h0) * WW;
    const float* fm0 = fm + (size_t)(b * 2 + 0) * PP * PP;
    const float* fm1 = fm + (size_t)(b * 2 + 1) * PP * PP;

    float acc0[ROWS], acc1[ROWS];
#pragma unroll
    for (int r = 0; r < ROWS; ++r) {                 // residual term
        acc0[r] = rg0[r * WW + w];
        acc1[r] = rg1[r * WW + w];
    }

#pragma unroll 4
    for (int k4 = 0; k4 < PP; k4 += 4) {
        float f0[4], f1[4];
#pragma unroll
        for (int t = 0; t < 4; ++t) {
            f0[t] = fm0[(size_t)(k4 + t) * PP + w];  // coalesced vector load
            f1[t] = fm1[(size_t)(k4 + t) * PP + w];
        }
#pragma unroll
        for (int r = 0; r < ROWS; ++r) {
            float4 a0 = *(const float4*)(rg0 + r * WW + k4);   // uniform -> s_load
            float4 a1 = *(const float4*)(rg1 + r * WW + k4);
            acc0[r] += a0.x * f0[0] + a0.y * f0[1] + a0.z * f0[2] + a0.w * f0[3];
            acc1[r] += a1.x * f1[0] + a1.y * f1[1] + a1.z * f1[2] + a1.w * f1[3];
        }
    }

    float wa = w_fs[0], wb = w_fs[1], wc = w_fs[2], wd = w_fs[3];
#pragma unroll
    for (int r = 0; r < ROWS; ++r) {
        float m0 = acc0[r], m1 = acc1[r];
        float fs0 = wa * m0 + wb * m1;
        float fs1 = wc * m0 + wd * m1;
        float s0 = sar[((size_t)(b * 2 + 0) * HH + (h0 + r)) * WW + w];
        float s1 = sar[((size_t)(b * 2 + 1) * HH + (h0 + r)) * WW + w];
        float4 v = make_float4(s0, s1, fs0, fs1);
        *(float4*)(xp + (((size_t)b * HP + (h0 + r + 1)) * WP + (w + 1)) * 4) = v;
    }
}

// ---------------------------------------------------------------------------
// Kernel 3: offset conv + deformable bilinear + deform conv, 2 px/thread.
// Offset conv: pixel-pair vectors formed ONCE (prs, static idx), r-OUTER
// fully-unrolled accumulation into a local f32x2 -> v_pk_fma_f32, no scratch
// (R7's r-inner form left the 18-iter loop rolled -> off2[] spilled,
// WRITE_SIZE 21MB). Coord/clamp/g math packed (R7-verified); gathers/interp/
// combine scalar (R6-verified).
// ---------------------------------------------------------------------------
__global__ __launch_bounds__(256, 2) void k_deform(
        const float* __restrict__ w_p, const float* __restrict__ b_p,
        const float* __restrict__ w_dc, const float* __restrict__ xp,
        float* __restrict__ out) {
    int idx = blockIdx.x * 256 + threadIdx.x;   // 0 .. B*(H/2)*W-1
    int b = idx >> 17;                          // (H/2)*W = 131072 = 2^17
    int rem = idx & ((HH / 2) * WW - 1);
    int h2 = rem >> 7;                          // W = 128 = 2^7
    int w = rem & (WW - 1);
    int h = h2 * 2;                             // pixels (h,w) and (h+1,w)

    const float4* xpb = (const float4*)xp + (size_t)b * HP * WP;

    // 4 rows x 3 cols neighborhood (float4 = 4 channels per point)
    float4 nb4[4][3];
#pragma unroll
    for (int dy = 0; dy < 4; ++dy)
#pragma unroll
        for (int dx = 0; dx < 3; ++dx)
            nb4[dy][dx] = xpb[(h + dy) * WP + (w + dx)];

    // pixel-pair vectors, formed once, all static indexing
    f32x2 prs[3][3][4];
#pragma unroll
    for (int ky = 0; ky < 3; ++ky)
#pragma unroll
        for (int kx = 0; kx < 3; ++kx) {
            prs[ky][kx][0] = (f32x2){nb4[ky][kx].x, nb4[ky + 1][kx].x};
            prs[ky][kx][1] = (f32x2){nb4[ky][kx].y, nb4[ky + 1][kx].y};
            prs[ky][kx][2] = (f32x2){nb4[ky][kx].z, nb4[ky + 1][kx].z};
            prs[ky][kx][3] = (f32x2){nb4[ky][kx].w, nb4[ky + 1][kx].w};
        }

    // ---- offset conv: r-outer, local accumulator -> v_pk_fma_f32 ----
    f32x2 off2[18];
#pragma unroll
    for (int r = 0; r < 18; ++r) {
        float bias = b_p[r];                    // uniform -> s_load
        f32x2 s = (f32x2){bias, bias};
#pragma unroll
        for (int ky = 0; ky < 3; ++ky)
#pragma unroll
            for (int kx = 0; kx < 3; ++kx) {
                const float* wr = w_p + r * 36 + ky * 3 + kx;  // uniform s_load
                s += wr[0] * prs[ky][kx][0] + wr[9] * prs[ky][kx][1]
                   + wr[18] * prs[ky][kx][2] + wr[27] * prs[ky][kx][3];
            }
        off2[r] = s;
    }

    float acc0[2] = {0.f, 0.f};
    float acc1[2] = {0.f, 0.f};
#pragma unroll
    for (int n = 0; n < 9; ++n) {
        int pny = n / 3 - 1;
        int pnx = n % 3 - 1;
        // packed coordinates for the pixel pair
        f32x2 py2 = (f32x2){(float)(h + 1 + pny), (float)(h + 2 + pny)} + off2[n];
        f32x2 px2 = (float)(w + 1 + pnx) + off2[9 + n];
        f32x2 fy2 = {floorf(py2.x), floorf(py2.y)};
        f32x2 fx2 = {floorf(px2.x), floorf(px2.y)};
        f32x2 y0f = {fminf(fmaxf(fy2.x, 0.f), (float)(HP - 1)),
                     fminf(fmaxf(fy2.y, 0.f), (float)(HP - 1))};
        f32x2 y1f = {fminf(fmaxf(fy2.x + 1.f, 0.f), (float)(HP - 1)),
                     fminf(fmaxf(fy2.y + 1.f, 0.f), (float)(HP - 1))};
        f32x2 x0f = {fminf(fmaxf(fx2.x, 0.f), (float)(WP - 1)),
                     fminf(fmaxf(fx2.y, 0.f), (float)(WP - 1))};
        f32x2 x1f = {fminf(fmaxf(fx2.x + 1.f, 0.f), (float)(WP - 1)),
                     fminf(fmaxf(fx2.y + 1.f, 0.f), (float)(WP - 1))};
        f32x2 pyc = {fminf(fmaxf(py2.x, 0.f), (float)(HP - 1)),
                     fminf(fmaxf(py2.y, 0.f), (float)(HP - 1))};
        f32x2 pxc = {fminf(fmaxf(px2.x, 0.f), (float)(WP - 1)),
                     fminf(fmaxf(px2.y, 0.f), (float)(WP - 1))};
        f32x2 ay = 1.f + (y0f - pyc);
        f32x2 by = 1.f - (y1f - pyc);
        f32x2 ax = 1.f + (x0f - pxc);
        f32x2 bx = 1.f - (x1f - pxc);
        f32x2 glt = ay * ax, grb = by * bx, glb = ay * bx, grt = by * ax;

#pragma unroll
        for (int p = 0; p < 2; ++p) {
            int y0 = (int)(p ? y0f.y : y0f.x);
            int y1 = (int)(p ? y1f.y : y1f.x);
            int x0 = (int)(p ? x0f.y : x0f.x);
            int x1 = (int)(p ? x1f.y : x1f.x);
            float g_lt = p ? glt.y : glt.x;
            float g_rb = p ? grb.y : grb.x;
            float g_lb = p ? glb.y : glb.x;
            float g_rt = p ? grt.y : grt.x;

            int r0 = y0 * WP, r1 = y1 * WP;     // int32 addressing
            float4 v_lt = xpb[r0 + x0];
            float4 v_rb = xpb[r1 + x1];
            float4 v_lb = xpb[r0 + x1];
            float4 v_rt = xpb[r1 + x0];

            float vx = g_lt * v_lt.x + g_rb * v_rb.x + g_lb * v_lb.x + g_rt * v_rt.x;
            float vy = g_lt * v_lt.y + g_rb * v_rb.y + g_lb * v_lb.y + g_rt * v_rt.y;
            float vz = g_lt * v_lt.z + g_rb * v_rb.z + g_lb * v_lb.z + g_rt * v_rt.z;
            float vw = g_lt * v_lt.w + g_rb * v_rb.w + g_lb * v_lb.w + g_rt * v_rt.w;

            acc0[p] += vx * w_dc[0 * 36 + 0 * 9 + n] + vy * w_dc[0 * 36 + 1 * 9 + n]
                     + vz * w_dc[0 * 36 + 2 * 9 + n] + vw * w_dc[0 * 36 + 3 * 9 + n];
            acc1[p] += vx * w_dc[1 * 36 + 0 * 9 + n] + vy * w_dc[1 * 36 + 1 * 9 + n]
                     + vz * w_dc[1 * 36 + 2 * 9 + n] + vw * w_dc[1 * 36 + 3 * 9 + n];
        }
    }
#pragma unroll
    for (int p = 0; p < 2; ++p) {
        out[((size_t)(b * 2 + 0) * HH + (h + p)) * WW + w] = acc0[p];
        out[((size_t)(b * 2 + 1) * HH + (h + p)) * WW + w] = acc1[p];
    }
}

// ---------------------------------------------------------------------------
extern "C" void kernel_launch(void* const* d_in, const int* in_sizes, int n_in,
                              void* d_out, int out_size, void* d_ws, size_t ws_size,
                              hipStream_t stream) {
    const float* rgb  = (const float*)d_in[0];
    const float* sar  = (const float*)d_in[1];
    const float* w_fm = (const float*)d_in[2];
    const float* w_fs = (const float*)d_in[3];
    const float* w_p  = (const float*)d_in[4];
    const float* b_p  = (const float*)d_in[5];
    const float* w_dc = (const float*)d_in[6];
    float* out = (float*)d_out;

    // ws layout: fm [131072 f32] | xp [B*HP*WP float4]
    float* ws = (float*)d_ws;
    float* fm = ws;
    float* xp = ws + 131072;                           // 16B aligned

    k_fm<<<BB * 128, 128, 0, stream>>>(rgb, w_fm, fm, (float4*)xp);
    k_mat<<<BB * (HH / ROWS), 128, 0, stream>>>(rgb, sar, w_fs, fm, xp);
    k_deform<<<(BB * (HH / 2) * WW) / 256, 256, 0, stream>>>(w_p, b_p, w_dc, xp, out);
}